// Round 18
// baseline (187.674 us; speedup 1.0000x reference)
//
#include <hip/hip_runtime.h>

// GraphEncoder: 2-layer GNN, edge-MLP + scatter-mean.
//   cat(x_dst,x_src)@Wa = (x@Wa_top)[dst] + (x@Wa_bot)[src]
//   mean_agg(relu(pre)@Wb + bb) = mean_agg(relu(pre))@Wb + (cnt>0)*bb
// R18: agg = XCD-sliced (R8's L2-residency: 64-feat slice by bid%8, 32 edges /
//      32 segments in flight) + packed-fp16 math (R12: pk_add/pk_max, ~half the
//      VALU issue of scalar f32) + poison-slot padding (csr prefilled with index
//      N each run; Pbot row N = fp16 -inf so relu contributes exact 0 — no
//      predication, no tail). R13/R17 nulls showed aggs are the ~90us block.

#define NODE_DIM 128
#define HID 256
#define OUTD 128
#define CPAD 16    // ints per counter (64B line)
#define SLOTS 128  // csr slots per node (max deg ~60 for Poisson(32); guarded)

typedef __attribute__((ext_vector_type(8))) _Float16 f16x8;
typedef __attribute__((ext_vector_type(4))) float f32x4;
typedef __attribute__((ext_vector_type(2))) _Float16 h2;

__device__ __forceinline__ h2 bc2(unsigned u) {
    return __builtin_bit_cast(h2, u);
}
__device__ __forceinline__ ushort f2h(float x) {
    _Float16 h = (_Float16)x;
    return __builtin_bit_cast(ushort, h);
}

// ---------------- prep ----------------
// Weights -> fp16 transposed; zero padded counters; poison rows (fp16 -inf) for
// P1b/P2b row N; prefill fixed-stride csr with poison index N (int4 stores).
__global__ void prep_all(const float* __restrict__ W1a, const float* __restrict__ W1b,
                         const float* __restrict__ W2a, const float* __restrict__ W2b,
                         ushort* __restrict__ T1a, ushort* __restrict__ T1b,
                         ushort* __restrict__ T2a, ushort* __restrict__ T2b,
                         int* __restrict__ cnt_p, int N,
                         ushort* __restrict__ P1b, ushort* __restrict__ P2b,
                         int* __restrict__ csr) {
    int j = blockIdx.x * blockDim.x + threadIdx.x;
    if (j < 65536) {  // T1a [n<512][k<128]; src W1a [256][256]
        int n = j >> 7, k = j & 127;
        float v = (n < 256) ? W1a[k * 256 + n] : W1a[(128 + k) * 256 + (n - 256)];
        T1a[j] = f2h(v);
        return;
    }
    if (j < 131072) {  // T1b [n<256][k<256]; src W1b [256][256]
        int t = j - 65536;
        int n = t >> 8, k = t & 255;
        T1b[t] = f2h(W1b[k * 256 + n]);
        return;
    }
    if (j < 196608) {  // T2a [n<256][k<256]; src W2a [512][128]
        int t = j - 131072;
        int n = t >> 8, k = t & 255;
        float v = (n < 128) ? W2a[k * 128 + n] : W2a[(256 + k) * 128 + (n - 128)];
        T2a[t] = f2h(v);
        return;
    }
    if (j < 212992) {  // T2b [n<128][k<128]; src W2b [128][128]
        int t = j - 196608;
        int n = t >> 7, k = t & 127;
        T2b[t] = f2h(W2b[k * 128 + n]);
        return;
    }
    int k = j - 212992;
    if (k < N * CPAD) {  // zero padded counters
        cnt_p[k] = 0;
        return;
    }
    k -= N * CPAD;
    if (k < HID) {  // P1b poison row: fp16 -inf
        P1b[(size_t)N * HID + k] = 0xFC00;
        return;
    }
    k -= HID;
    if (k < OUTD) {  // P2b poison row
        P2b[(size_t)N * OUTD + k] = 0xFC00;
        return;
    }
    k -= OUTD;
    if (k < N * SLOTS / 4) {  // csr prefill with poison index N
        ((int4*)csr)[k] = make_int4(N, N, N, N);
    }
}

// ---------------- one-pass fixed-stride CSR build (2 edges/thread) ----------------
__global__ void scatter_hist(const int* __restrict__ src, const int* __restrict__ dst,
                             int* __restrict__ cnt_p, int* __restrict__ csr, int E) {
    int e = (blockIdx.x * blockDim.x + threadIdx.x) * 2;
    if (e + 1 < E) {
        int2 s = *(const int2*)(src + e);
        int2 d = *(const int2*)(dst + e);
        int p0 = atomicAdd(&cnt_p[(size_t)d.x * CPAD], 1);
        if (p0 < SLOTS) csr[(size_t)d.x * SLOTS + p0] = s.x;
        int p1 = atomicAdd(&cnt_p[(size_t)d.y * CPAD], 1);
        if (p1 < SLOTS) csr[(size_t)d.y * SLOTS + p1] = s.y;
    } else if (e < E) {
        int p = atomicAdd(&cnt_p[(size_t)dst[e] * CPAD], 1);
        if (p < SLOTS) csr[(size_t)dst[e] * SLOTS + p] = src[e];
    }
}

// ---------------- fp16 1-pass MFMA GEMM ----------------
// A[M][K]: fp16 (AF32=0) or f32 with in-staging conversion (AF32=1).
// B transposed [Nc][K] fp16. Tile BM=128, BN=128, BK=32; 4 waves, wave tile
// 64x64. MODE 0: f32 out (+bias*gate). MODE 1: dual — col<nsplit -> f32+bias;
// col>=nsplit -> fp16. MODE 3: fp16 out (+bias*gate, relu).
// gate is a strided int array (gate[row*gstride] > 0).

#define GBM 128
#define GBN 128
#define GBK 32
#define LDSW 40

template <int MODE, int AF32>
__global__ __launch_bounds__(256) void gemm_h(
    const void* __restrict__ Av, int M, int K,
    const ushort* __restrict__ BT,
    const float* __restrict__ bias, const int* __restrict__ gate, int gstride,
    int relu, float* __restrict__ Cf, ushort* __restrict__ Ch, int Nc, int nsplit) {
    __shared__ ushort sA[GBM * LDSW];
    __shared__ ushort sB[GBN * LDSW];

    const int tid = threadIdx.x;
    const int lane = tid & 63;
    const int w = tid >> 6;
    const int wm = w >> 1, wn = w & 1;
    const int r16 = lane & 15, kg = lane >> 4;
    const int m0 = blockIdx.x * GBM;
    const int n0 = blockIdx.y * GBN;

    const int arow = tid >> 1, ahalf = tid & 1;  // 2 thr/row, 16 ushorts each

    f32x4 acc[4][4];
#pragma unroll
    for (int i = 0; i < 4; i++)
#pragma unroll
        for (int j = 0; j < 4; j++) acc[i][j] = (f32x4)0.f;

    for (int kt = 0; kt < K; kt += GBK) {
        {
            const int gr = m0 + arow;
            ushort* d = sA + arow * LDSW + ahalf * 16;
            if constexpr (AF32) {
                const float* Af = (const float*)Av;
                float4 v0 = make_float4(0.f, 0.f, 0.f, 0.f), v1 = v0, v2 = v0, v3 = v0;
                if (gr < M) {
                    const float* p = Af + (size_t)gr * K + kt + ahalf * 16;
                    v0 = ((const float4*)p)[0];
                    v1 = ((const float4*)p)[1];
                    v2 = ((const float4*)p)[2];
                    v3 = ((const float4*)p)[3];
                }
                ushort4 h0, h1, h2_, h3;
                h0.x = f2h(v0.x); h0.y = f2h(v0.y); h0.z = f2h(v0.z); h0.w = f2h(v0.w);
                h1.x = f2h(v1.x); h1.y = f2h(v1.y); h1.z = f2h(v1.z); h1.w = f2h(v1.w);
                h2_.x = f2h(v2.x); h2_.y = f2h(v2.y); h2_.z = f2h(v2.z); h2_.w = f2h(v2.w);
                h3.x = f2h(v3.x); h3.y = f2h(v3.y); h3.z = f2h(v3.z); h3.w = f2h(v3.w);
                ((ushort4*)d)[0] = h0;
                ((ushort4*)d)[1] = h1;
                ((ushort4*)d)[2] = h2_;
                ((ushort4*)d)[3] = h3;
            } else {
                const ushort* Ah = (const ushort*)Av;
                const size_t go = (size_t)gr * K + kt + ahalf * 16;
                int4 a0 = make_int4(0, 0, 0, 0), a1 = a0;
                if (gr < M) {
                    a0 = *(const int4*)(Ah + go);
                    a1 = *(const int4*)(Ah + go + 8);
                }
                *(int4*)(d) = a0;
                *(int4*)(d + 8) = a1;
            }
        }
        {
            const size_t go = (size_t)(n0 + arow) * K + kt + ahalf * 16;
            int4 b0 = *(const int4*)(BT + go);
            int4 b1 = *(const int4*)(BT + go + 8);
            ushort* d = sB + arow * LDSW + ahalf * 16;
            *(int4*)(d) = b0;
            *(int4*)(d + 8) = b1;
        }
        __syncthreads();

        f16x8 av[4], bv[4];
#pragma unroll
        for (int mi = 0; mi < 4; mi++)
            av[mi] = *(const f16x8*)(sA + (wm * 64 + mi * 16 + r16) * LDSW + kg * 8);
#pragma unroll
        for (int ni = 0; ni < 4; ni++)
            bv[ni] = *(const f16x8*)(sB + (wn * 64 + ni * 16 + r16) * LDSW + kg * 8);
#pragma unroll
        for (int mi = 0; mi < 4; mi++)
#pragma unroll
            for (int ni = 0; ni < 4; ni++)
                acc[mi][ni] = __builtin_amdgcn_mfma_f32_16x16x32_f16(av[mi], bv[ni], acc[mi][ni], 0, 0, 0);
        __syncthreads();
    }

    // epilogue: C/D mapping col=lane&15, row=(lane>>4)*4+reg  [m89-verified]
#pragma unroll
    for (int ni = 0; ni < 4; ni++) {
        const int col = n0 + wn * 64 + ni * 16 + r16;
        float bv = 0.f;
        if constexpr (MODE == 1) {
            bv = (col < nsplit && bias) ? bias[col] : 0.f;
        } else {
            bv = bias ? bias[col] : 0.f;
        }
#pragma unroll
        for (int mi = 0; mi < 4; mi++) {
#pragma unroll
            for (int r = 0; r < 4; r++) {
                const int row = m0 + wm * 64 + mi * 16 + kg * 4 + r;
                if (row >= M) continue;
                if constexpr (MODE == 1) {
                    const float v = acc[mi][ni][r];
                    if (col < nsplit) {
                        Cf[(size_t)row * nsplit + col] = v + bv;
                    } else {
                        Ch[(size_t)row * (Nc - nsplit) + (col - nsplit)] = f2h(v);
                    }
                } else {
                    float g = 1.f;
                    if (gate) g = (gate[(size_t)row * gstride] > 0) ? 1.f : 0.f;
                    float v = acc[mi][ni][r] + bv * g;
                    if (relu) v = fmaxf(v, 0.f);
                    const size_t o = (size_t)row * Nc + col;
                    if constexpr (MODE == 0) {
                        Cf[o] = v;
                    } else {
                        Ch[o] = f2h(v);
                    }
                }
            }
        }
    }
}

// ---------------- agg: XCD-sliced, packed fp16, poison-padded ----------------
// Slice = 64 feats chosen by XCD (bid%8) -> per-XCD resident Pbot slice
// N*128B = 2.56MB < 4MB L2. Wave per (node, slice). fq=lane&15 picks a feature
// quad (ushort4 = 2x h2); es=lane>>4 picks edge group: each slot loads 4 edges
// -> 8 slots = 32 edges / 32 segments in flight, NO predication (pad slots hold
// poison index N; Pbot row N = fp16 -inf -> max(t+(-inf),0) = 0 exactly).
// h2 accumulate per 32-edge iter (8 values/lane), f32 flush; shfl_xor combine.

template <int H>
__global__ __launch_bounds__(256) void agg_s(const float* __restrict__ Ptop,
                                             const ushort* __restrict__ Pbot,
                                             const int* __restrict__ cnt_p,
                                             const int* __restrict__ csr,
                                             ushort* __restrict__ S, int N) {
    constexpr int SLICES = H / 64;   // 4 (H=256) or 2 (H=128)
    constexpr int XPS = 8 / SLICES;  // XCDs per slice

    const int bid = blockIdx.x;
    const int xcd = bid & 7;
    const int grp = bid >> 3;
    const int slice = xcd / XPS;
    const int subx = xcd % XPS;
    const int wave = threadIdx.x >> 6;
    const int lane = threadIdx.x & 63;

    const int n = (grp * XPS + subx) * 4 + wave;
    if (n >= N) return;
    const int qoff = slice * 64;

    const int fq = lane & 15;  // feature quad (4 feats, 8B)
    const int es = lane >> 4;  // edge group 0..3

    int deg = cnt_p[(size_t)n * CPAD];
    if (deg > SLOTS) deg = SLOTS;
    const int dpad = (deg + 31) & ~31;
    const int begin = n * SLOTS;

    const float4 tf = *(const float4*)(Ptop + (size_t)n * H + qoff + fq * 4);
    const h2 t01 = (h2){(_Float16)tf.x, (_Float16)tf.y};
    const h2 t23 = (h2){(_Float16)tf.z, (_Float16)tf.w};
    const h2 z2 = (h2)(_Float16)0.f;

    float a0 = 0.f, a1 = 0.f, a2 = 0.f, a3 = 0.f;
    const ushort* pb = Pbot + qoff + fq * 4;

    for (int e = begin; e < begin + dpad; e += 32) {
        int idx[8];
#pragma unroll
        for (int j = 0; j < 8; j++) idx[j] = csr[e + j * 4 + es];
        uint2 v[8];
#pragma unroll
        for (int j = 0; j < 8; j++)
            v[j] = *(const uint2*)(pb + (size_t)idx[j] * H);
        h2 p01 = z2, p23 = z2;
#pragma unroll
        for (int j = 0; j < 8; j++) {
            p01 += __builtin_elementwise_max(t01 + bc2(v[j].x), z2);
            p23 += __builtin_elementwise_max(t23 + bc2(v[j].y), z2);
        }
        a0 += (float)p01.x;
        a1 += (float)p01.y;
        a2 += (float)p23.x;
        a3 += (float)p23.y;
    }

    // combine the 4 edge groups (lanes differing in bits 4,5)
    a0 += __shfl_xor(a0, 16, 64);
    a1 += __shfl_xor(a1, 16, 64);
    a2 += __shfl_xor(a2, 16, 64);
    a3 += __shfl_xor(a3, 16, 64);
    a0 += __shfl_xor(a0, 32, 64);
    a1 += __shfl_xor(a1, 32, 64);
    a2 += __shfl_xor(a2, 32, 64);
    a3 += __shfl_xor(a3, 32, 64);

    if (es == 0) {
        const float inv = (deg > 0) ? 1.f / (float)deg : 0.f;
        ushort4 h;
        h.x = f2h(a0 * inv);
        h.y = f2h(a1 * inv);
        h.z = f2h(a2 * inv);
        h.w = f2h(a3 * inv);
        *(ushort4*)(S + (size_t)n * H + qoff + fq * 4) = h;
    }
}

// ---------------- launch ----------------

extern "C" void kernel_launch(void* const* d_in, const int* in_sizes, int n_in,
                              void* d_out, int out_size, void* d_ws, size_t ws_size,
                              hipStream_t stream) {
    const int N = in_sizes[0] / NODE_DIM;  // 20000
    const int E = in_sizes[1] / 2;         // 640000

    const float* x = (const float*)d_in[0];
    const int* ei = (const int*)d_in[1];
    const int* e_src = ei;
    const int* e_dst = ei + E;
    const float* W1a = (const float*)d_in[2];
    const float* b1a = (const float*)d_in[3];
    const float* W1b = (const float*)d_in[4];
    const float* b1b = (const float*)d_in[5];
    const float* W2a = (const float*)d_in[6];
    const float* b2a = (const float*)d_in[7];
    const float* W2b = (const float*)d_in[8];
    const float* b2b = (const float*)d_in[9];

    char* ws = (char*)d_ws;
    size_t off = 0;
    auto alloc = [&](size_t bytes) {
        size_t o = off;
        off += (bytes + 255) & ~(size_t)255;
        return o;
    };
    int* cnt_p = (int*)(ws + alloc((size_t)N * CPAD * 4));  // padded cursors/counts
    int* csr = (int*)(ws + alloc((size_t)N * SLOTS * 4));   // fixed-stride CSR
    ushort* T1a = (ushort*)(ws + alloc((size_t)(2 * HID) * NODE_DIM * 2));  // [512][128]
    ushort* T1b = (ushort*)(ws + alloc((size_t)HID * HID * 2));
    ushort* T2a = (ushort*)(ws + alloc((size_t)(2 * OUTD) * HID * 2));  // [256][256]
    ushort* T2b = (ushort*)(ws + alloc((size_t)OUTD * OUTD * 2));
    float* P1t = (float*)(ws + alloc((size_t)N * HID * 4));
    ushort* P1b = (ushort*)(ws + alloc((size_t)(N + 1) * HID * 2));   // fp16 + poison row
    ushort* P2b = (ushort*)(ws + alloc((size_t)(N + 1) * OUTD * 2));  // fp16 + poison row
    ushort* S1 = (ushort*)(ws + alloc((size_t)N * HID * 2));          // fp16
    ushort* S2 = (ushort*)(ws + alloc((size_t)N * OUTD * 2));         // fp16
    ushort* h_h = (ushort*)(ws + alloc((size_t)N * HID * 2));         // fp16
    float* P2t = P1t;

    const int MT = (N + GBM - 1) / GBM;  // 157
    // agg grids: 8 * ceil(N / (4 nodes/block * XPS)), XPS = 8/(H/64)
    const int AG1 = 8 * ((N + 4 * 2 - 1) / (4 * 2));  // H=256: 20000 blocks
    const int AG2 = 8 * ((N + 4 * 4 - 1) / (4 * 4));  // H=128: 10000 blocks

    // K1: prep (weights + counters + poison rows + csr prefill)
    const int prep_n = 212992 + N * CPAD + HID + OUTD + N * SLOTS / 4;
    prep_all<<<(prep_n + 255) / 256, 256, 0, stream>>>(
        W1a, W1b, W2a, W2b, T1a, T1b, T2a, T2b, cnt_p, N, P1b, P2b, csr);

    // K2: one-pass CSR build (2 edges/thread)
    scatter_hist<<<((E + 1) / 2 + 255) / 256, 256, 0, stream>>>(e_src, e_dst, cnt_p, csr, E);

    // K3: layer-1 merged projection from f32 x (Nc=512: [P1t f32+b1a | P1b fp16])
    gemm_h<1, 1><<<dim3(MT, (2 * HID) / GBN), 256, 0, stream>>>(
        x, N, NODE_DIM, T1a, b1a, nullptr, 0, 0, P1t, P1b, 2 * HID, HID);

    // K4: agg layer 1 (XCD-sliced)
    agg_s<HID><<<AG1, 256, 0, stream>>>(P1t, P1b, cnt_p, csr, S1, N);

    // K5: S1@W1b -> h (fp16, bias gated by deg, relu)
    gemm_h<3, 0><<<dim3(MT, HID / GBN), 256, 0, stream>>>(
        S1, N, HID, T1b, b1b, cnt_p, CPAD, 1, nullptr, h_h, HID, 0);

    // K6: layer-2 merged projection (Nc=256: [P2t f32+b2a | P2b fp16])
    gemm_h<1, 0><<<dim3(MT, (2 * OUTD) / GBN), 256, 0, stream>>>(
        h_h, N, HID, T2a, b2a, nullptr, 0, 0, P2t, P2b, 2 * OUTD, OUTD);

    // K7: agg layer 2 (XCD-sliced)
    agg_s<OUTD><<<AG2, 256, 0, stream>>>(P2t, P2b, cnt_p, csr, S2, N);

    // K8: final GEMM -> f32 out (+b2b gated by deg)
    gemm_h<0, 0><<<dim3(MT, OUTD / GBN), 256, 0, stream>>>(
        S2, N, OUTD, T2b, b2b, cnt_p, CPAD, 0, (float*)d_out, nullptr, OUTD, 0);
}

// Round 19
// 187.660 us; speedup vs baseline: 1.0001x; 1.0001x over previous
//
#include <hip/hip_runtime.h>

// GraphEncoder: 2-layer GNN, edge-MLP + scatter-mean.
//   cat(x_dst,x_src)@Wa = (x@Wa_top)[dst] + (x@Wa_bot)[src]
//   mean_agg(relu(pre)@Wb + bb) = mean_agg(relu(pre))@Wb + (cnt>0)*bb
// R19: revert to R16 (178us champion; R17 AF32-G1 and R18 sliced-agg both
//      regressed). One change: agg_f uses 4 edge-split waves per node
//      (1 node/block) -> ~1 serial 8-edge gather round per wave instead of 2.
//      Full-row waves, wave-uniform edge loop, packed fp16 math, exact deg.

#define NODE_DIM 128
#define HID 256
#define OUTD 128
#define CPAD 16    // ints per counter (64B line)
#define SLOTS 128  // csr slots per node (max deg ~60 for Poisson(32); guarded)

typedef __attribute__((ext_vector_type(8))) _Float16 f16x8;
typedef __attribute__((ext_vector_type(4))) float f32x4;
typedef __attribute__((ext_vector_type(2))) _Float16 h2;

__device__ __forceinline__ h2 bc2(unsigned u) {
    return __builtin_bit_cast(h2, u);
}
__device__ __forceinline__ ushort f2h(float x) {
    _Float16 h = (_Float16)x;
    return __builtin_bit_cast(ushort, h);
}

// ---------------- prep ----------------
// Fused: x -> fp16, weight transposes -> fp16, padded counter zero.
__global__ void prep_all(const float* __restrict__ x, int nx4,
                         ushort* __restrict__ x_h,
                         const float* __restrict__ W1a, const float* __restrict__ W1b,
                         const float* __restrict__ W2a, const float* __restrict__ W2b,
                         ushort* __restrict__ T1a, ushort* __restrict__ T1b,
                         ushort* __restrict__ T2a, ushort* __restrict__ T2b,
                         int* __restrict__ cnt_p, int N) {
    int i = blockIdx.x * blockDim.x + threadIdx.x;
    if (i < nx4) {
        float4 v = ((const float4*)x)[i];
        ushort4 h;
        h.x = f2h(v.x);
        h.y = f2h(v.y);
        h.z = f2h(v.z);
        h.w = f2h(v.w);
        ((ushort4*)x_h)[i] = h;
        return;
    }
    int j = i - nx4;
    if (j < 65536) {  // T1a [n<512][k<128]; src W1a [256][256]
        int n = j >> 7, k = j & 127;
        float v = (n < 256) ? W1a[k * 256 + n] : W1a[(128 + k) * 256 + (n - 256)];
        T1a[j] = f2h(v);
        return;
    }
    if (j < 131072) {  // T1b [n<256][k<256]; src W1b [256][256]
        int t = j - 65536;
        int n = t >> 8, k = t & 255;
        T1b[t] = f2h(W1b[k * 256 + n]);
        return;
    }
    if (j < 196608) {  // T2a [n<256][k<256]; src W2a [512][128]
        int t = j - 131072;
        int n = t >> 8, k = t & 255;
        float v = (n < 128) ? W2a[k * 128 + n] : W2a[(256 + k) * 128 + (n - 128)];
        T2a[t] = f2h(v);
        return;
    }
    if (j < 212992) {  // T2b [n<128][k<128]; src W2b [128][128]
        int t = j - 196608;
        int n = t >> 7, k = t & 127;
        T2b[t] = f2h(W2b[k * 128 + n]);
        return;
    }
    int k = j - 212992;
    if (k < N * CPAD) cnt_p[k] = 0;
}

// ---------------- one-pass fixed-stride CSR build ----------------
// csr[dst*SLOTS + p] = src, p = atomicAdd(padded cursor). No hist, no scan.
__global__ void scatter_hist(const int* __restrict__ src, const int* __restrict__ dst,
                             int* __restrict__ cnt_p, int* __restrict__ csr, int E) {
    int e = blockIdx.x * blockDim.x + threadIdx.x;
    if (e < E) {
        const int d = dst[e];
        int p = atomicAdd(&cnt_p[(size_t)d * CPAD], 1);
        if (p < SLOTS) csr[(size_t)d * SLOTS + p] = src[e];
    }
}

// ---------------- fp16 1-pass MFMA GEMM ----------------
// A[M][K] fp16; B transposed [Nc][K] fp16. Tile BM=128, BN=128, BK=32; 4 waves
// (2m x 2n), wave tile 64x64. MODE 0: f32 out (+bias*gate). MODE 1: dual —
// col<nsplit -> f32+bias; col>=nsplit -> fp16. MODE 3: fp16 out (+bias*gate, relu).
// gate is a strided int array (gate[row*gstride] > 0).

#define GBM 128
#define GBN 128
#define GBK 32
#define LDSW 40

template <int MODE>
__global__ __launch_bounds__(256) void gemm_h(
    const ushort* __restrict__ A, int M, int K,
    const ushort* __restrict__ BT,
    const float* __restrict__ bias, const int* __restrict__ gate, int gstride,
    int relu, float* __restrict__ Cf, ushort* __restrict__ Ch, int Nc, int nsplit) {
    __shared__ ushort sA[GBM * LDSW];
    __shared__ ushort sB[GBN * LDSW];

    const int tid = threadIdx.x;
    const int lane = tid & 63;
    const int w = tid >> 6;
    const int wm = w >> 1, wn = w & 1;
    const int r16 = lane & 15, kg = lane >> 4;
    const int m0 = blockIdx.x * GBM;
    const int n0 = blockIdx.y * GBN;

    const int arow = tid >> 1, ahalf = tid & 1;  // 2 thr/row, 16 ushorts (2x int4)

    f32x4 acc[4][4];
#pragma unroll
    for (int i = 0; i < 4; i++)
#pragma unroll
        for (int j = 0; j < 4; j++) acc[i][j] = (f32x4)0.f;

    for (int kt = 0; kt < K; kt += GBK) {
        {
            const int gr = m0 + arow;
            const size_t go = (size_t)gr * K + kt + ahalf * 16;
            int4 a0 = make_int4(0, 0, 0, 0), a1 = a0;
            if (gr < M) {
                a0 = *(const int4*)(A + go);
                a1 = *(const int4*)(A + go + 8);
            }
            ushort* d = sA + arow * LDSW + ahalf * 16;
            *(int4*)(d) = a0;
            *(int4*)(d + 8) = a1;
        }
        {
            const size_t go = (size_t)(n0 + arow) * K + kt + ahalf * 16;
            int4 b0 = *(const int4*)(BT + go);
            int4 b1 = *(const int4*)(BT + go + 8);
            ushort* d = sB + arow * LDSW + ahalf * 16;
            *(int4*)(d) = b0;
            *(int4*)(d + 8) = b1;
        }
        __syncthreads();

        f16x8 av[4], bv[4];
#pragma unroll
        for (int mi = 0; mi < 4; mi++)
            av[mi] = *(const f16x8*)(sA + (wm * 64 + mi * 16 + r16) * LDSW + kg * 8);
#pragma unroll
        for (int ni = 0; ni < 4; ni++)
            bv[ni] = *(const f16x8*)(sB + (wn * 64 + ni * 16 + r16) * LDSW + kg * 8);
#pragma unroll
        for (int mi = 0; mi < 4; mi++)
#pragma unroll
            for (int ni = 0; ni < 4; ni++)
                acc[mi][ni] = __builtin_amdgcn_mfma_f32_16x16x32_f16(av[mi], bv[ni], acc[mi][ni], 0, 0, 0);
        __syncthreads();
    }

    // epilogue: C/D mapping col=lane&15, row=(lane>>4)*4+reg  [m89-verified]
#pragma unroll
    for (int ni = 0; ni < 4; ni++) {
        const int col = n0 + wn * 64 + ni * 16 + r16;
        float bv = 0.f;
        if constexpr (MODE == 1) {
            bv = (col < nsplit && bias) ? bias[col] : 0.f;
        } else {
            bv = bias ? bias[col] : 0.f;
        }
#pragma unroll
        for (int mi = 0; mi < 4; mi++) {
#pragma unroll
            for (int r = 0; r < 4; r++) {
                const int row = m0 + wm * 64 + mi * 16 + kg * 4 + r;
                if (row >= M) continue;
                if constexpr (MODE == 1) {
                    const float v = acc[mi][ni][r];
                    if (col < nsplit) {
                        Cf[(size_t)row * nsplit + col] = v + bv;
                    } else {
                        Ch[(size_t)row * (Nc - nsplit) + (col - nsplit)] = f2h(v);
                    }
                } else {
                    float g = 1.f;
                    if (gate) g = (gate[(size_t)row * gstride] > 0) ? 1.f : 0.f;
                    float v = acc[mi][ni][r] + bv * g;
                    if (relu) v = fmaxf(v, 0.f);
                    const size_t o = (size_t)row * Nc + col;
                    if constexpr (MODE == 0) {
                        Cf[o] = v;
                    } else {
                        Ch[o] = f2h(v);
                    }
                }
            }
        }
    }
}

// ---------------- CSR mean aggregation: full-row waves, uniform edge loop -------
// Wave = one node's full H-feature row (lane = feature column, VPL feats/lane).
// 4 waves per node (1 node/block) split the edge list by 8-edge groups; edge
// indices are wave-uniform (scalar loads), gathers fully coalesced. Packed fp16
// math, f32 flush per 8-edge group. Fixed-stride CSR: begin=n*SLOTS, deg=cnt_p.

template <int H>
__global__ __launch_bounds__(256) void agg_f(const float* __restrict__ Ptop,
                                             const ushort* __restrict__ Pbot,
                                             const int* __restrict__ cnt_p,
                                             const int* __restrict__ csr,
                                             ushort* __restrict__ S, int N) {
    constexpr int VPL = H / 64;  // feats per lane: 4 (H=256) or 2 (H=128)
    __shared__ float red[3][64 * VPL];

    const int tid = threadIdx.x;
    const int lane = tid & 63;
    const int sub = __builtin_amdgcn_readfirstlane(tid >> 6);  // edge-split 0..3
    const int n = blockIdx.x;

    int deg = cnt_p[(size_t)n * CPAD];
    if (deg > SLOTS) deg = SLOTS;  // impossible for this input; guards OOB
    const int begin = n * SLOTS;

    h2 t01, t23;
    if constexpr (VPL == 4) {
        float4 tf = *(const float4*)(Ptop + (size_t)n * H + lane * 4);
        t01 = (h2){(_Float16)tf.x, (_Float16)tf.y};
        t23 = (h2){(_Float16)tf.z, (_Float16)tf.w};
    } else {
        float2 tf = *(const float2*)(Ptop + (size_t)n * H + lane * 2);
        t01 = (h2){(_Float16)tf.x, (_Float16)tf.y};
        t23 = t01;
    }
    const h2 z2 = (h2)(_Float16)0.f;

    float a0 = 0.f, a1 = 0.f, a2 = 0.f, a3 = 0.f;
    const ushort* pb = Pbot + lane * VPL;

    const int Gf = deg >> 3;  // full 8-edge groups
    const int r = deg & 7;

    for (int g = sub; g < Gf; g += 4) {
        const int e = begin + g * 8;
        h2 p01 = z2, p23 = z2;
#pragma unroll
        for (int j = 0; j < 8; j++) {
            const int idx = csr[e + j];
            if constexpr (VPL == 4) {
                uint2 u = *(const uint2*)(pb + (size_t)idx * H);
                p01 += __builtin_elementwise_max(t01 + bc2(u.x), z2);
                p23 += __builtin_elementwise_max(t23 + bc2(u.y), z2);
            } else {
                unsigned u = *(const unsigned*)(pb + (size_t)idx * H);
                p01 += __builtin_elementwise_max(t01 + bc2(u), z2);
            }
        }
        a0 += (float)p01.x;
        a1 += (float)p01.y;
        if constexpr (VPL == 4) {
            a2 += (float)p23.x;
            a3 += (float)p23.y;
        }
    }
    if (r && sub == (Gf & 3)) {  // tail to the wave after the last full group
        const int e = begin + Gf * 8;
        h2 p01 = z2, p23 = z2;
        for (int j = 0; j < r; j++) {
            const int idx = csr[e + j];
            if constexpr (VPL == 4) {
                uint2 u = *(const uint2*)(pb + (size_t)idx * H);
                p01 += __builtin_elementwise_max(t01 + bc2(u.x), z2);
                p23 += __builtin_elementwise_max(t23 + bc2(u.y), z2);
            } else {
                unsigned u = *(const unsigned*)(pb + (size_t)idx * H);
                p01 += __builtin_elementwise_max(t01 + bc2(u), z2);
            }
        }
        a0 += (float)p01.x;
        a1 += (float)p01.y;
        if constexpr (VPL == 4) {
            a2 += (float)p23.x;
            a3 += (float)p23.y;
        }
    }

    // combine the 4 edge-split waves via LDS
    if (sub != 0) {
        red[sub - 1][lane * VPL + 0] = a0;
        red[sub - 1][lane * VPL + 1] = a1;
        if constexpr (VPL == 4) {
            red[sub - 1][lane * VPL + 2] = a2;
            red[sub - 1][lane * VPL + 3] = a3;
        }
    }
    __syncthreads();
    if (sub == 0) {
#pragma unroll
        for (int s = 0; s < 3; s++) {
            a0 += red[s][lane * VPL + 0];
            a1 += red[s][lane * VPL + 1];
            if constexpr (VPL == 4) {
                a2 += red[s][lane * VPL + 2];
                a3 += red[s][lane * VPL + 3];
            }
        }
        const float inv = (deg > 0) ? 1.f / (float)deg : 0.f;
        if constexpr (VPL == 4) {
            ushort4 h;
            h.x = f2h(a0 * inv);
            h.y = f2h(a1 * inv);
            h.z = f2h(a2 * inv);
            h.w = f2h(a3 * inv);
            *(ushort4*)(S + (size_t)n * H + lane * 4) = h;
        } else {
            ushort2 h;
            h.x = f2h(a0 * inv);
            h.y = f2h(a1 * inv);
            *(ushort2*)(S + (size_t)n * H + lane * 2) = h;
        }
    }
}

// ---------------- launch ----------------

extern "C" void kernel_launch(void* const* d_in, const int* in_sizes, int n_in,
                              void* d_out, int out_size, void* d_ws, size_t ws_size,
                              hipStream_t stream) {
    const int N = in_sizes[0] / NODE_DIM;  // 20000
    const int E = in_sizes[1] / 2;         // 640000

    const float* x = (const float*)d_in[0];
    const int* ei = (const int*)d_in[1];
    const int* e_src = ei;
    const int* e_dst = ei + E;
    const float* W1a = (const float*)d_in[2];
    const float* b1a = (const float*)d_in[3];
    const float* W1b = (const float*)d_in[4];
    const float* b1b = (const float*)d_in[5];
    const float* W2a = (const float*)d_in[6];
    const float* b2a = (const float*)d_in[7];
    const float* W2b = (const float*)d_in[8];
    const float* b2b = (const float*)d_in[9];

    char* ws = (char*)d_ws;
    size_t off = 0;
    auto alloc = [&](size_t bytes) {
        size_t o = off;
        off += (bytes + 255) & ~(size_t)255;
        return o;
    };
    int* cnt_p = (int*)(ws + alloc((size_t)N * CPAD * 4));  // padded cursors/counts
    int* csr = (int*)(ws + alloc((size_t)N * SLOTS * 4));   // fixed-stride CSR
    ushort* x_h = (ushort*)(ws + alloc((size_t)N * NODE_DIM * 2));
    ushort* T1a = (ushort*)(ws + alloc((size_t)(2 * HID) * NODE_DIM * 2));  // [512][128]
    ushort* T1b = (ushort*)(ws + alloc((size_t)HID * HID * 2));
    ushort* T2a = (ushort*)(ws + alloc((size_t)(2 * OUTD) * HID * 2));  // [256][256]
    ushort* T2b = (ushort*)(ws + alloc((size_t)OUTD * OUTD * 2));
    float* P1t = (float*)(ws + alloc((size_t)N * HID * 4));
    ushort* P1b = (ushort*)(ws + alloc((size_t)N * HID * 2));   // fp16
    ushort* P2b = (ushort*)(ws + alloc((size_t)N * OUTD * 2));  // fp16
    ushort* S1 = (ushort*)(ws + alloc((size_t)N * HID * 2));    // fp16
    ushort* S2 = (ushort*)(ws + alloc((size_t)N * OUTD * 2));   // fp16
    ushort* h_h = (ushort*)(ws + alloc((size_t)N * HID * 2));   // fp16
    float* P2t = P1t;

    const int MT = (N + GBM - 1) / GBM;  // 157

    // K1: prep (padded counter zero inside)
    const int nx4 = N * NODE_DIM / 4;
    const int prep_n = nx4 + 212992 + N * CPAD;
    prep_all<<<(prep_n + 255) / 256, 256, 0, stream>>>(
        x, nx4, x_h, W1a, W1b, W2a, W2b, T1a, T1b, T2a, T2b, cnt_p, N);

    // K2: one-pass CSR build (hist+scan+scatter collapsed)
    scatter_hist<<<(E + 255) / 256, 256, 0, stream>>>(e_src, e_dst, cnt_p, csr, E);

    // K3: layer-1 merged projection (Nc=512: [P1t f32+b1a | P1b fp16])
    gemm_h<1><<<dim3(MT, (2 * HID) / GBN), 256, 0, stream>>>(
        x_h, N, NODE_DIM, T1a, b1a, nullptr, 0, 0, P1t, P1b, 2 * HID, HID);

    // K4: agg layer 1 (4 waves/node)
    agg_f<HID><<<N, 256, 0, stream>>>(P1t, P1b, cnt_p, csr, S1, N);

    // K5: S1@W1b -> h (fp16, bias gated by deg, relu)
    gemm_h<3><<<dim3(MT, HID / GBN), 256, 0, stream>>>(
        S1, N, HID, T1b, b1b, cnt_p, CPAD, 1, nullptr, h_h, HID, 0);

    // K6: layer-2 merged projection (Nc=256: [P2t f32+b2a | P2b fp16])
    gemm_h<1><<<dim3(MT, (2 * OUTD) / GBN), 256, 0, stream>>>(
        h_h, N, HID, T2a, b2a, nullptr, 0, 0, P2t, P2b, 2 * OUTD, OUTD);

    // K7: agg layer 2 (4 waves/node)
    agg_f<OUTD><<<N, 256, 0, stream>>>(P2t, P2b, cnt_p, csr, S2, N);

    // K8: final GEMM -> f32 out (+b2b gated by deg)
    gemm_h<0><<<dim3(MT, OUTD / GBN), 256, 0, stream>>>(
        S2, N, OUTD, T2b, b2b, cnt_p, CPAD, 0, (float*)d_out, nullptr, OUTD, 0);
}

// Round 20
// 181.058 us; speedup vs baseline: 1.0365x; 1.0365x over previous
//
#include <hip/hip_runtime.h>

// GraphEncoder: 2-layer GNN, edge-MLP + scatter-mean.
//   cat(x_dst,x_src)@Wa = (x@Wa_top)[dst] + (x@Wa_bot)[src]
//   mean_agg(relu(pre)@Wb + bb) = mean_agg(relu(pre))@Wb + (cnt>0)*bb
// R20: exact R16 (178us champion) + grid-stride PERSISTENT agg: 2048 blocks,
//      each wave-pair loops nodes with stride gridDim*2 (amortize block
//      launch/drain, overlap next node's csr/top loads with current math).
//      R18/R19 showed more-smaller-blocks regresses; this goes the other way.

#define NODE_DIM 128
#define HID 256
#define OUTD 128
#define CPAD 16    // ints per counter (64B line)
#define SLOTS 128  // csr slots per node (max deg ~60 for Poisson(32); guarded)

typedef __attribute__((ext_vector_type(8))) _Float16 f16x8;
typedef __attribute__((ext_vector_type(4))) float f32x4;
typedef __attribute__((ext_vector_type(2))) _Float16 h2;

__device__ __forceinline__ h2 bc2(unsigned u) {
    return __builtin_bit_cast(h2, u);
}
__device__ __forceinline__ ushort f2h(float x) {
    _Float16 h = (_Float16)x;
    return __builtin_bit_cast(ushort, h);
}

// ---------------- prep ----------------
// Fused: x -> fp16, weight transposes -> fp16, padded counter zero.
__global__ void prep_all(const float* __restrict__ x, int nx4,
                         ushort* __restrict__ x_h,
                         const float* __restrict__ W1a, const float* __restrict__ W1b,
                         const float* __restrict__ W2a, const float* __restrict__ W2b,
                         ushort* __restrict__ T1a, ushort* __restrict__ T1b,
                         ushort* __restrict__ T2a, ushort* __restrict__ T2b,
                         int* __restrict__ cnt_p, int N) {
    int i = blockIdx.x * blockDim.x + threadIdx.x;
    if (i < nx4) {
        float4 v = ((const float4*)x)[i];
        ushort4 h;
        h.x = f2h(v.x);
        h.y = f2h(v.y);
        h.z = f2h(v.z);
        h.w = f2h(v.w);
        ((ushort4*)x_h)[i] = h;
        return;
    }
    int j = i - nx4;
    if (j < 65536) {  // T1a [n<512][k<128]; src W1a [256][256]
        int n = j >> 7, k = j & 127;
        float v = (n < 256) ? W1a[k * 256 + n] : W1a[(128 + k) * 256 + (n - 256)];
        T1a[j] = f2h(v);
        return;
    }
    if (j < 131072) {  // T1b [n<256][k<256]; src W1b [256][256]
        int t = j - 65536;
        int n = t >> 8, k = t & 255;
        T1b[t] = f2h(W1b[k * 256 + n]);
        return;
    }
    if (j < 196608) {  // T2a [n<256][k<256]; src W2a [512][128]
        int t = j - 131072;
        int n = t >> 8, k = t & 255;
        float v = (n < 128) ? W2a[k * 128 + n] : W2a[(256 + k) * 128 + (n - 128)];
        T2a[t] = f2h(v);
        return;
    }
    if (j < 212992) {  // T2b [n<128][k<128]; src W2b [128][128]
        int t = j - 196608;
        int n = t >> 7, k = t & 127;
        T2b[t] = f2h(W2b[k * 128 + n]);
        return;
    }
    int k = j - 212992;
    if (k < N * CPAD) cnt_p[k] = 0;
}

// ---------------- one-pass fixed-stride CSR build ----------------
// csr[dst*SLOTS + p] = src, p = atomicAdd(padded cursor). No hist, no scan.
__global__ void scatter_hist(const int* __restrict__ src, const int* __restrict__ dst,
                             int* __restrict__ cnt_p, int* __restrict__ csr, int E) {
    int e = blockIdx.x * blockDim.x + threadIdx.x;
    if (e < E) {
        const int d = dst[e];
        int p = atomicAdd(&cnt_p[(size_t)d * CPAD], 1);
        if (p < SLOTS) csr[(size_t)d * SLOTS + p] = src[e];
    }
}

// ---------------- fp16 1-pass MFMA GEMM ----------------
// A[M][K] fp16; B transposed [Nc][K] fp16. Tile BM=128, BN=128, BK=32; 4 waves
// (2m x 2n), wave tile 64x64. MODE 0: f32 out (+bias*gate). MODE 1: dual —
// col<nsplit -> f32+bias; col>=nsplit -> fp16. MODE 3: fp16 out (+bias*gate, relu).
// gate is a strided int array (gate[row*gstride] > 0).

#define GBM 128
#define GBN 128
#define GBK 32
#define LDSW 40

template <int MODE>
__global__ __launch_bounds__(256) void gemm_h(
    const ushort* __restrict__ A, int M, int K,
    const ushort* __restrict__ BT,
    const float* __restrict__ bias, const int* __restrict__ gate, int gstride,
    int relu, float* __restrict__ Cf, ushort* __restrict__ Ch, int Nc, int nsplit) {
    __shared__ ushort sA[GBM * LDSW];
    __shared__ ushort sB[GBN * LDSW];

    const int tid = threadIdx.x;
    const int lane = tid & 63;
    const int w = tid >> 6;
    const int wm = w >> 1, wn = w & 1;
    const int r16 = lane & 15, kg = lane >> 4;
    const int m0 = blockIdx.x * GBM;
    const int n0 = blockIdx.y * GBN;

    const int arow = tid >> 1, ahalf = tid & 1;  // 2 thr/row, 16 ushorts (2x int4)

    f32x4 acc[4][4];
#pragma unroll
    for (int i = 0; i < 4; i++)
#pragma unroll
        for (int j = 0; j < 4; j++) acc[i][j] = (f32x4)0.f;

    for (int kt = 0; kt < K; kt += GBK) {
        {
            const int gr = m0 + arow;
            const size_t go = (size_t)gr * K + kt + ahalf * 16;
            int4 a0 = make_int4(0, 0, 0, 0), a1 = a0;
            if (gr < M) {
                a0 = *(const int4*)(A + go);
                a1 = *(const int4*)(A + go + 8);
            }
            ushort* d = sA + arow * LDSW + ahalf * 16;
            *(int4*)(d) = a0;
            *(int4*)(d + 8) = a1;
        }
        {
            const size_t go = (size_t)(n0 + arow) * K + kt + ahalf * 16;
            int4 b0 = *(const int4*)(BT + go);
            int4 b1 = *(const int4*)(BT + go + 8);
            ushort* d = sB + arow * LDSW + ahalf * 16;
            *(int4*)(d) = b0;
            *(int4*)(d + 8) = b1;
        }
        __syncthreads();

        f16x8 av[4], bv[4];
#pragma unroll
        for (int mi = 0; mi < 4; mi++)
            av[mi] = *(const f16x8*)(sA + (wm * 64 + mi * 16 + r16) * LDSW + kg * 8);
#pragma unroll
        for (int ni = 0; ni < 4; ni++)
            bv[ni] = *(const f16x8*)(sB + (wn * 64 + ni * 16 + r16) * LDSW + kg * 8);
#pragma unroll
        for (int mi = 0; mi < 4; mi++)
#pragma unroll
            for (int ni = 0; ni < 4; ni++)
                acc[mi][ni] = __builtin_amdgcn_mfma_f32_16x16x32_f16(av[mi], bv[ni], acc[mi][ni], 0, 0, 0);
        __syncthreads();
    }

    // epilogue: C/D mapping col=lane&15, row=(lane>>4)*4+reg  [m89-verified]
#pragma unroll
    for (int ni = 0; ni < 4; ni++) {
        const int col = n0 + wn * 64 + ni * 16 + r16;
        float bv = 0.f;
        if constexpr (MODE == 1) {
            bv = (col < nsplit && bias) ? bias[col] : 0.f;
        } else {
            bv = bias ? bias[col] : 0.f;
        }
#pragma unroll
        for (int mi = 0; mi < 4; mi++) {
#pragma unroll
            for (int r = 0; r < 4; r++) {
                const int row = m0 + wm * 64 + mi * 16 + kg * 4 + r;
                if (row >= M) continue;
                if constexpr (MODE == 1) {
                    const float v = acc[mi][ni][r];
                    if (col < nsplit) {
                        Cf[(size_t)row * nsplit + col] = v + bv;
                    } else {
                        Ch[(size_t)row * (Nc - nsplit) + (col - nsplit)] = f2h(v);
                    }
                } else {
                    float g = 1.f;
                    if (gate) g = (gate[(size_t)row * gstride] > 0) ? 1.f : 0.f;
                    float v = acc[mi][ni][r] + bv * g;
                    if (relu) v = fmaxf(v, 0.f);
                    const size_t o = (size_t)row * Nc + col;
                    if constexpr (MODE == 0) {
                        Cf[o] = v;
                    } else {
                        Ch[o] = f2h(v);
                    }
                }
            }
        }
    }
}

// ---------------- CSR mean aggregation: persistent grid-stride ----------------
// Wave = one node's full H-feature row (lane = feature column, VPL feats/lane).
// 2 waves per node split the edge list by 8-edge groups (wave-uniform scalar
// edge indices, fully coalesced row gathers, packed fp16 math, f32 flush per
// group). 2048 blocks grid-stride over nodes: amortizes block launch/drain and
// overlaps next node's csr/top loads with current node's math.

template <int H>
__global__ __launch_bounds__(256) void agg_f(const float* __restrict__ Ptop,
                                             const ushort* __restrict__ Pbot,
                                             const int* __restrict__ cnt_p,
                                             const int* __restrict__ csr,
                                             ushort* __restrict__ S, int N) {
    constexpr int VPL = H / 64;  // feats per lane: 4 (H=256) or 2 (H=128)
    __shared__ float red[2][64 * VPL];

    const int tid = threadIdx.x;
    const int lane = tid & 63;
    const int wv = __builtin_amdgcn_readfirstlane(tid >> 6);
    const int nb = wv >> 1;   // node slot within block (0,1)
    const int sub = wv & 1;   // edge-split half
    const int stride = gridDim.x * 2;

    for (int n = blockIdx.x * 2 + nb; n < N; n += stride) {
        int deg = cnt_p[(size_t)n * CPAD];
        if (deg > SLOTS) deg = SLOTS;  // impossible for this input; guards OOB
        const int begin = n * SLOTS;

        h2 t01, t23;
        if constexpr (VPL == 4) {
            float4 tf = *(const float4*)(Ptop + (size_t)n * H + lane * 4);
            t01 = (h2){(_Float16)tf.x, (_Float16)tf.y};
            t23 = (h2){(_Float16)tf.z, (_Float16)tf.w};
        } else {
            float2 tf = *(const float2*)(Ptop + (size_t)n * H + lane * 2);
            t01 = (h2){(_Float16)tf.x, (_Float16)tf.y};
            t23 = t01;
        }
        const h2 z2 = (h2)(_Float16)0.f;

        float a0 = 0.f, a1 = 0.f, a2 = 0.f, a3 = 0.f;
        const ushort* pb = Pbot + lane * VPL;

        const int Gf = deg >> 3;  // full 8-edge groups
        const int r = deg & 7;

        for (int g = sub; g < Gf; g += 2) {
            const int e = begin + g * 8;
            h2 p01 = z2, p23 = z2;
#pragma unroll
            for (int j = 0; j < 8; j++) {
                const int idx = csr[e + j];
                if constexpr (VPL == 4) {
                    uint2 u = *(const uint2*)(pb + (size_t)idx * H);
                    p01 += __builtin_elementwise_max(t01 + bc2(u.x), z2);
                    p23 += __builtin_elementwise_max(t23 + bc2(u.y), z2);
                } else {
                    unsigned u = *(const unsigned*)(pb + (size_t)idx * H);
                    p01 += __builtin_elementwise_max(t01 + bc2(u), z2);
                }
            }
            a0 += (float)p01.x;
            a1 += (float)p01.y;
            if constexpr (VPL == 4) {
                a2 += (float)p23.x;
                a3 += (float)p23.y;
            }
        }
        if (r && sub == (Gf & 1)) {  // tail to the wave with fewer groups
            const int e = begin + Gf * 8;
            h2 p01 = z2, p23 = z2;
            for (int j = 0; j < r; j++) {
                const int idx = csr[e + j];
                if constexpr (VPL == 4) {
                    uint2 u = *(const uint2*)(pb + (size_t)idx * H);
                    p01 += __builtin_elementwise_max(t01 + bc2(u.x), z2);
                    p23 += __builtin_elementwise_max(t23 + bc2(u.y), z2);
                } else {
                    unsigned u = *(const unsigned*)(pb + (size_t)idx * H);
                    p01 += __builtin_elementwise_max(t01 + bc2(u), z2);
                }
            }
            a0 += (float)p01.x;
            a1 += (float)p01.y;
            if constexpr (VPL == 4) {
                a2 += (float)p23.x;
                a3 += (float)p23.y;
            }
        }

        // combine the two edge-split waves via LDS (buffer reused per iter)
        if (sub == 1) {
            red[nb][lane * VPL + 0] = a0;
            red[nb][lane * VPL + 1] = a1;
            if constexpr (VPL == 4) {
                red[nb][lane * VPL + 2] = a2;
                red[nb][lane * VPL + 3] = a3;
            }
        }
        __syncthreads();
        if (sub == 0) {
            a0 += red[nb][lane * VPL + 0];
            a1 += red[nb][lane * VPL + 1];
            if constexpr (VPL == 4) {
                a2 += red[nb][lane * VPL + 2];
                a3 += red[nb][lane * VPL + 3];
            }
            const float inv = (deg > 0) ? 1.f / (float)deg : 0.f;
            if constexpr (VPL == 4) {
                ushort4 h;
                h.x = f2h(a0 * inv);
                h.y = f2h(a1 * inv);
                h.z = f2h(a2 * inv);
                h.w = f2h(a3 * inv);
                *(ushort4*)(S + (size_t)n * H + lane * 4) = h;
            } else {
                ushort2 h;
                h.x = f2h(a0 * inv);
                h.y = f2h(a1 * inv);
                *(ushort2*)(S + (size_t)n * H + lane * 2) = h;
            }
        }
        __syncthreads();  // protect red[] before next iteration's writes
    }
}

// ---------------- launch ----------------

extern "C" void kernel_launch(void* const* d_in, const int* in_sizes, int n_in,
                              void* d_out, int out_size, void* d_ws, size_t ws_size,
                              hipStream_t stream) {
    const int N = in_sizes[0] / NODE_DIM;  // 20000
    const int E = in_sizes[1] / 2;         // 640000

    const float* x = (const float*)d_in[0];
    const int* ei = (const int*)d_in[1];
    const int* e_src = ei;
    const int* e_dst = ei + E;
    const float* W1a = (const float*)d_in[2];
    const float* b1a = (const float*)d_in[3];
    const float* W1b = (const float*)d_in[4];
    const float* b1b = (const float*)d_in[5];
    const float* W2a = (const float*)d_in[6];
    const float* b2a = (const float*)d_in[7];
    const float* W2b = (const float*)d_in[8];
    const float* b2b = (const float*)d_in[9];

    char* ws = (char*)d_ws;
    size_t off = 0;
    auto alloc = [&](size_t bytes) {
        size_t o = off;
        off += (bytes + 255) & ~(size_t)255;
        return o;
    };
    int* cnt_p = (int*)(ws + alloc((size_t)N * CPAD * 4));  // padded cursors/counts
    int* csr = (int*)(ws + alloc((size_t)N * SLOTS * 4));   // fixed-stride CSR
    ushort* x_h = (ushort*)(ws + alloc((size_t)N * NODE_DIM * 2));
    ushort* T1a = (ushort*)(ws + alloc((size_t)(2 * HID) * NODE_DIM * 2));  // [512][128]
    ushort* T1b = (ushort*)(ws + alloc((size_t)HID * HID * 2));
    ushort* T2a = (ushort*)(ws + alloc((size_t)(2 * OUTD) * HID * 2));  // [256][256]
    ushort* T2b = (ushort*)(ws + alloc((size_t)OUTD * OUTD * 2));
    float* P1t = (float*)(ws + alloc((size_t)N * HID * 4));
    ushort* P1b = (ushort*)(ws + alloc((size_t)N * HID * 2));   // fp16
    ushort* P2b = (ushort*)(ws + alloc((size_t)N * OUTD * 2));  // fp16
    ushort* S1 = (ushort*)(ws + alloc((size_t)N * HID * 2));    // fp16
    ushort* S2 = (ushort*)(ws + alloc((size_t)N * OUTD * 2));   // fp16
    ushort* h_h = (ushort*)(ws + alloc((size_t)N * HID * 2));   // fp16
    float* P2t = P1t;

    const int MT = (N + GBM - 1) / GBM;  // 157
    const int AG = 2048;                 // persistent agg blocks (grid-stride)

    // K1: prep (padded counter zero inside)
    const int nx4 = N * NODE_DIM / 4;
    const int prep_n = nx4 + 212992 + N * CPAD;
    prep_all<<<(prep_n + 255) / 256, 256, 0, stream>>>(
        x, nx4, x_h, W1a, W1b, W2a, W2b, T1a, T1b, T2a, T2b, cnt_p, N);

    // K2: one-pass CSR build (hist+scan+scatter collapsed)
    scatter_hist<<<(E + 255) / 256, 256, 0, stream>>>(e_src, e_dst, cnt_p, csr, E);

    // K3: layer-1 merged projection (Nc=512: [P1t f32+b1a | P1b fp16])
    gemm_h<1><<<dim3(MT, (2 * HID) / GBN), 256, 0, stream>>>(
        x_h, N, NODE_DIM, T1a, b1a, nullptr, 0, 0, P1t, P1b, 2 * HID, HID);

    // K4: agg layer 1 (persistent)
    agg_f<HID><<<AG, 256, 0, stream>>>(P1t, P1b, cnt_p, csr, S1, N);

    // K5: S1@W1b -> h (fp16, bias gated by deg, relu)
    gemm_h<3><<<dim3(MT, HID / GBN), 256, 0, stream>>>(
        S1, N, HID, T1b, b1b, cnt_p, CPAD, 1, nullptr, h_h, HID, 0);

    // K6: layer-2 merged projection (Nc=256: [P2t f32+b2a | P2b fp16])
    gemm_h<1><<<dim3(MT, (2 * OUTD) / GBN), 256, 0, stream>>>(
        h_h, N, HID, T2a, b2a, nullptr, 0, 0, P2t, P2b, 2 * OUTD, OUTD);

    // K7: agg layer 2 (persistent)
    agg_f<OUTD><<<AG, 256, 0, stream>>>(P2t, P2b, cnt_p, csr, S2, N);

    // K8: final GEMM -> f32 out (+b2b gated by deg)
    gemm_h<0><<<dim3(MT, OUTD / GBN), 256, 0, stream>>>(
        S2, N, OUTD, T2b, b2b, cnt_p, CPAD, 0, (float*)d_out, nullptr, OUTD, 0);
}

// Round 21
// 175.262 us; speedup vs baseline: 1.0708x; 1.0331x over previous
//
#include <hip/hip_runtime.h>

// GraphEncoder: 2-layer GNN, edge-MLP + scatter-mean.
//   cat(x_dst,x_src)@Wa = (x@Wa_top)[dst] + (x@Wa_bot)[src]
//   mean_agg(relu(pre)@Wb + bb) = mean_agg(relu(pre))@Wb + (cnt>0)*bb
// R21: R16 champion structure + P1t/P2t stored fp16 (agg converted them to fp16
//      at load anyway — f32 storage was a pure 60MB HBM round-trip waste; bias
//      folded before the RNE round, bit-identical to before). Agg loads h2
//      directly (no cvt). All else = R16.

#define NODE_DIM 128
#define HID 256
#define OUTD 128
#define CPAD 16    // ints per counter (64B line)
#define SLOTS 128  // csr slots per node (max deg ~60 for Poisson(32); guarded)

typedef __attribute__((ext_vector_type(8))) _Float16 f16x8;
typedef __attribute__((ext_vector_type(4))) float f32x4;
typedef __attribute__((ext_vector_type(2))) _Float16 h2;

__device__ __forceinline__ h2 bc2(unsigned u) {
    return __builtin_bit_cast(h2, u);
}
__device__ __forceinline__ ushort f2h(float x) {
    _Float16 h = (_Float16)x;
    return __builtin_bit_cast(ushort, h);
}

// ---------------- prep ----------------
// Fused: x -> fp16, weight transposes -> fp16, padded counter zero.
__global__ void prep_all(const float* __restrict__ x, int nx4,
                         ushort* __restrict__ x_h,
                         const float* __restrict__ W1a, const float* __restrict__ W1b,
                         const float* __restrict__ W2a, const float* __restrict__ W2b,
                         ushort* __restrict__ T1a, ushort* __restrict__ T1b,
                         ushort* __restrict__ T2a, ushort* __restrict__ T2b,
                         int* __restrict__ cnt_p, int N) {
    int i = blockIdx.x * blockDim.x + threadIdx.x;
    if (i < nx4) {
        float4 v = ((const float4*)x)[i];
        ushort4 h;
        h.x = f2h(v.x);
        h.y = f2h(v.y);
        h.z = f2h(v.z);
        h.w = f2h(v.w);
        ((ushort4*)x_h)[i] = h;
        return;
    }
    int j = i - nx4;
    if (j < 65536) {  // T1a [n<512][k<128]; src W1a [256][256]
        int n = j >> 7, k = j & 127;
        float v = (n < 256) ? W1a[k * 256 + n] : W1a[(128 + k) * 256 + (n - 256)];
        T1a[j] = f2h(v);
        return;
    }
    if (j < 131072) {  // T1b [n<256][k<256]; src W1b [256][256]
        int t = j - 65536;
        int n = t >> 8, k = t & 255;
        T1b[t] = f2h(W1b[k * 256 + n]);
        return;
    }
    if (j < 196608) {  // T2a [n<256][k<256]; src W2a [512][128]
        int t = j - 131072;
        int n = t >> 8, k = t & 255;
        float v = (n < 128) ? W2a[k * 128 + n] : W2a[(256 + k) * 128 + (n - 128)];
        T2a[t] = f2h(v);
        return;
    }
    if (j < 212992) {  // T2b [n<128][k<128]; src W2b [128][128]
        int t = j - 196608;
        int n = t >> 7, k = t & 127;
        T2b[t] = f2h(W2b[k * 128 + n]);
        return;
    }
    int k = j - 212992;
    if (k < N * CPAD) cnt_p[k] = 0;
}

// ---------------- one-pass fixed-stride CSR build ----------------
// csr[dst*SLOTS + p] = src, p = atomicAdd(padded cursor). No hist, no scan.
__global__ void scatter_hist(const int* __restrict__ src, const int* __restrict__ dst,
                             int* __restrict__ cnt_p, int* __restrict__ csr, int E) {
    int e = blockIdx.x * blockDim.x + threadIdx.x;
    if (e < E) {
        const int d = dst[e];
        int p = atomicAdd(&cnt_p[(size_t)d * CPAD], 1);
        if (p < SLOTS) csr[(size_t)d * SLOTS + p] = src[e];
    }
}

// ---------------- fp16 1-pass MFMA GEMM ----------------
// A[M][K] fp16; B transposed [Nc][K] fp16. Tile BM=128, BN=128, BK=32; 4 waves
// (2m x 2n), wave tile 64x64. MODE 0: f32 out (+bias*gate). MODE 1: dual fp16 —
// col<nsplit -> Ch (fp16, +bias); col>=nsplit -> Ch2 (fp16). MODE 3: fp16 out
// (+bias*gate, relu). gate is a strided int array (gate[row*gstride] > 0).

#define GBM 128
#define GBN 128
#define GBK 32
#define LDSW 40

template <int MODE>
__global__ __launch_bounds__(256) void gemm_h(
    const ushort* __restrict__ A, int M, int K,
    const ushort* __restrict__ BT,
    const float* __restrict__ bias, const int* __restrict__ gate, int gstride,
    int relu, float* __restrict__ Cf, ushort* __restrict__ Ch,
    ushort* __restrict__ Ch2, int Nc, int nsplit) {
    __shared__ ushort sA[GBM * LDSW];
    __shared__ ushort sB[GBN * LDSW];

    const int tid = threadIdx.x;
    const int lane = tid & 63;
    const int w = tid >> 6;
    const int wm = w >> 1, wn = w & 1;
    const int r16 = lane & 15, kg = lane >> 4;
    const int m0 = blockIdx.x * GBM;
    const int n0 = blockIdx.y * GBN;

    const int arow = tid >> 1, ahalf = tid & 1;  // 2 thr/row, 16 ushorts (2x int4)

    f32x4 acc[4][4];
#pragma unroll
    for (int i = 0; i < 4; i++)
#pragma unroll
        for (int j = 0; j < 4; j++) acc[i][j] = (f32x4)0.f;

    for (int kt = 0; kt < K; kt += GBK) {
        {
            const int gr = m0 + arow;
            const size_t go = (size_t)gr * K + kt + ahalf * 16;
            int4 a0 = make_int4(0, 0, 0, 0), a1 = a0;
            if (gr < M) {
                a0 = *(const int4*)(A + go);
                a1 = *(const int4*)(A + go + 8);
            }
            ushort* d = sA + arow * LDSW + ahalf * 16;
            *(int4*)(d) = a0;
            *(int4*)(d + 8) = a1;
        }
        {
            const size_t go = (size_t)(n0 + arow) * K + kt + ahalf * 16;
            int4 b0 = *(const int4*)(BT + go);
            int4 b1 = *(const int4*)(BT + go + 8);
            ushort* d = sB + arow * LDSW + ahalf * 16;
            *(int4*)(d) = b0;
            *(int4*)(d + 8) = b1;
        }
        __syncthreads();

        f16x8 av[4], bv[4];
#pragma unroll
        for (int mi = 0; mi < 4; mi++)
            av[mi] = *(const f16x8*)(sA + (wm * 64 + mi * 16 + r16) * LDSW + kg * 8);
#pragma unroll
        for (int ni = 0; ni < 4; ni++)
            bv[ni] = *(const f16x8*)(sB + (wn * 64 + ni * 16 + r16) * LDSW + kg * 8);
#pragma unroll
        for (int mi = 0; mi < 4; mi++)
#pragma unroll
            for (int ni = 0; ni < 4; ni++)
                acc[mi][ni] = __builtin_amdgcn_mfma_f32_16x16x32_f16(av[mi], bv[ni], acc[mi][ni], 0, 0, 0);
        __syncthreads();
    }

    // epilogue: C/D mapping col=lane&15, row=(lane>>4)*4+reg  [m89-verified]
#pragma unroll
    for (int ni = 0; ni < 4; ni++) {
        const int col = n0 + wn * 64 + ni * 16 + r16;
        float bv = 0.f;
        if constexpr (MODE == 1) {
            bv = (col < nsplit && bias) ? bias[col] : 0.f;
        } else {
            bv = bias ? bias[col] : 0.f;
        }
#pragma unroll
        for (int mi = 0; mi < 4; mi++) {
#pragma unroll
            for (int r = 0; r < 4; r++) {
                const int row = m0 + wm * 64 + mi * 16 + kg * 4 + r;
                if (row >= M) continue;
                if constexpr (MODE == 1) {
                    const float v = acc[mi][ni][r];
                    if (col < nsplit) {
                        Ch[(size_t)row * nsplit + col] = f2h(v + bv);
                    } else {
                        Ch2[(size_t)row * (Nc - nsplit) + (col - nsplit)] = f2h(v);
                    }
                } else {
                    float g = 1.f;
                    if (gate) g = (gate[(size_t)row * gstride] > 0) ? 1.f : 0.f;
                    float v = acc[mi][ni][r] + bv * g;
                    if (relu) v = fmaxf(v, 0.f);
                    const size_t o = (size_t)row * Nc + col;
                    if constexpr (MODE == 0) {
                        Cf[o] = v;
                    } else {
                        Ch[o] = f2h(v);
                    }
                }
            }
        }
    }
}

// ---------------- CSR mean aggregation: full-row waves, uniform edge loop -------
// Wave = one node's full H-feature row (lane = feature column, VPL feats/lane).
// 2 waves per node split the edge list by 8-edge groups; edge indices are
// wave-uniform (scalar loads), gathers fully coalesced. Ptop now fp16 (h2 load,
// no cvt). Packed fp16 math, f32 flush per 8-edge group. Fixed-stride CSR.

template <int H>
__global__ __launch_bounds__(256) void agg_f(const ushort* __restrict__ Ptop,
                                             const ushort* __restrict__ Pbot,
                                             const int* __restrict__ cnt_p,
                                             const int* __restrict__ csr,
                                             ushort* __restrict__ S, int N) {
    constexpr int VPL = H / 64;  // feats per lane: 4 (H=256) or 2 (H=128)
    __shared__ float red[2][64 * VPL];

    const int tid = threadIdx.x;
    const int lane = tid & 63;
    const int wv = __builtin_amdgcn_readfirstlane(tid >> 6);
    const int nb = wv >> 1;   // node within block (0,1)
    const int sub = wv & 1;   // edge-split half
    int n = blockIdx.x * 2 + nb;
    if (n >= N) n = N - 1;  // benign duplicate on tail

    int deg = cnt_p[(size_t)n * CPAD];
    if (deg > SLOTS) deg = SLOTS;  // impossible for this input; guards OOB
    const int begin = n * SLOTS;

    h2 t01, t23;
    if constexpr (VPL == 4) {
        uint2 tu = *(const uint2*)(Ptop + (size_t)n * H + lane * 4);
        t01 = bc2(tu.x);
        t23 = bc2(tu.y);
    } else {
        unsigned tu = *(const unsigned*)(Ptop + (size_t)n * H + lane * 2);
        t01 = bc2(tu);
        t23 = t01;
    }
    const h2 z2 = (h2)(_Float16)0.f;

    float a0 = 0.f, a1 = 0.f, a2 = 0.f, a3 = 0.f;
    const ushort* pb = Pbot + lane * VPL;

    const int Gf = deg >> 3;  // full 8-edge groups
    const int r = deg & 7;

    for (int g = sub; g < Gf; g += 2) {
        const int e = begin + g * 8;
        h2 p01 = z2, p23 = z2;
#pragma unroll
        for (int j = 0; j < 8; j++) {
            const int idx = csr[e + j];
            if constexpr (VPL == 4) {
                uint2 u = *(const uint2*)(pb + (size_t)idx * H);
                p01 += __builtin_elementwise_max(t01 + bc2(u.x), z2);
                p23 += __builtin_elementwise_max(t23 + bc2(u.y), z2);
            } else {
                unsigned u = *(const unsigned*)(pb + (size_t)idx * H);
                p01 += __builtin_elementwise_max(t01 + bc2(u), z2);
            }
        }
        a0 += (float)p01.x;
        a1 += (float)p01.y;
        if constexpr (VPL == 4) {
            a2 += (float)p23.x;
            a3 += (float)p23.y;
        }
    }
    if (r && sub == (Gf & 1)) {  // tail to the wave with fewer groups
        const int e = begin + Gf * 8;
        h2 p01 = z2, p23 = z2;
        for (int j = 0; j < r; j++) {
            const int idx = csr[e + j];
            if constexpr (VPL == 4) {
                uint2 u = *(const uint2*)(pb + (size_t)idx * H);
                p01 += __builtin_elementwise_max(t01 + bc2(u.x), z2);
                p23 += __builtin_elementwise_max(t23 + bc2(u.y), z2);
            } else {
                unsigned u = *(const unsigned*)(pb + (size_t)idx * H);
                p01 += __builtin_elementwise_max(t01 + bc2(u), z2);
            }
        }
        a0 += (float)p01.x;
        a1 += (float)p01.y;
        if constexpr (VPL == 4) {
            a2 += (float)p23.x;
            a3 += (float)p23.y;
        }
    }

    // combine the two edge-split waves via LDS
    if (sub == 1) {
        red[nb][lane * VPL + 0] = a0;
        red[nb][lane * VPL + 1] = a1;
        if constexpr (VPL == 4) {
            red[nb][lane * VPL + 2] = a2;
            red[nb][lane * VPL + 3] = a3;
        }
    }
    __syncthreads();
    if (sub == 0) {
        a0 += red[nb][lane * VPL + 0];
        a1 += red[nb][lane * VPL + 1];
        if constexpr (VPL == 4) {
            a2 += red[nb][lane * VPL + 2];
            a3 += red[nb][lane * VPL + 3];
        }
        const float inv = (deg > 0) ? 1.f / (float)deg : 0.f;
        if constexpr (VPL == 4) {
            ushort4 h;
            h.x = f2h(a0 * inv);
            h.y = f2h(a1 * inv);
            h.z = f2h(a2 * inv);
            h.w = f2h(a3 * inv);
            *(ushort4*)(S + (size_t)n * H + lane * 4) = h;
        } else {
            ushort2 h;
            h.x = f2h(a0 * inv);
            h.y = f2h(a1 * inv);
            *(ushort2*)(S + (size_t)n * H + lane * 2) = h;
        }
    }
}

// ---------------- launch ----------------

extern "C" void kernel_launch(void* const* d_in, const int* in_sizes, int n_in,
                              void* d_out, int out_size, void* d_ws, size_t ws_size,
                              hipStream_t stream) {
    const int N = in_sizes[0] / NODE_DIM;  // 20000
    const int E = in_sizes[1] / 2;         // 640000

    const float* x = (const float*)d_in[0];
    const int* ei = (const int*)d_in[1];
    const int* e_src = ei;
    const int* e_dst = ei + E;
    const float* W1a = (const float*)d_in[2];
    const float* b1a = (const float*)d_in[3];
    const float* W1b = (const float*)d_in[4];
    const float* b1b = (const float*)d_in[5];
    const float* W2a = (const float*)d_in[6];
    const float* b2a = (const float*)d_in[7];
    const float* W2b = (const float*)d_in[8];
    const float* b2b = (const float*)d_in[9];

    char* ws = (char*)d_ws;
    size_t off = 0;
    auto alloc = [&](size_t bytes) {
        size_t o = off;
        off += (bytes + 255) & ~(size_t)255;
        return o;
    };
    int* cnt_p = (int*)(ws + alloc((size_t)N * CPAD * 4));  // padded cursors/counts
    int* csr = (int*)(ws + alloc((size_t)N * SLOTS * 4));   // fixed-stride CSR
    ushort* x_h = (ushort*)(ws + alloc((size_t)N * NODE_DIM * 2));
    ushort* T1a = (ushort*)(ws + alloc((size_t)(2 * HID) * NODE_DIM * 2));  // [512][128]
    ushort* T1b = (ushort*)(ws + alloc((size_t)HID * HID * 2));
    ushort* T2a = (ushort*)(ws + alloc((size_t)(2 * OUTD) * HID * 2));  // [256][256]
    ushort* T2b = (ushort*)(ws + alloc((size_t)OUTD * OUTD * 2));
    ushort* P1t = (ushort*)(ws + alloc((size_t)N * HID * 2));   // fp16 (was f32)
    ushort* P1b = (ushort*)(ws + alloc((size_t)N * HID * 2));   // fp16
    ushort* P2b = (ushort*)(ws + alloc((size_t)N * OUTD * 2));  // fp16
    ushort* S1 = (ushort*)(ws + alloc((size_t)N * HID * 2));    // fp16
    ushort* S2 = (ushort*)(ws + alloc((size_t)N * OUTD * 2));   // fp16
    ushort* h_h = (ushort*)(ws + alloc((size_t)N * HID * 2));   // fp16
    ushort* P2t = P1t;

    const int MT = (N + GBM - 1) / GBM;  // 157
    const int AG = (N + 1) / 2;          // agg blocks: 2 nodes x 2 edge-split waves

    // K1: prep (padded counter zero inside)
    const int nx4 = N * NODE_DIM / 4;
    const int prep_n = nx4 + 212992 + N * CPAD;
    prep_all<<<(prep_n + 255) / 256, 256, 0, stream>>>(
        x, nx4, x_h, W1a, W1b, W2a, W2b, T1a, T1b, T2a, T2b, cnt_p, N);

    // K2: one-pass CSR build (hist+scan+scatter collapsed)
    scatter_hist<<<(E + 255) / 256, 256, 0, stream>>>(e_src, e_dst, cnt_p, csr, E);

    // K3: layer-1 merged projection (Nc=512: [P1t fp16+b1a | P1b fp16])
    gemm_h<1><<<dim3(MT, (2 * HID) / GBN), 256, 0, stream>>>(
        x_h, N, NODE_DIM, T1a, b1a, nullptr, 0, 0, nullptr, P1t, P1b, 2 * HID, HID);

    // K4: agg layer 1
    agg_f<HID><<<AG, 256, 0, stream>>>(P1t, P1b, cnt_p, csr, S1, N);

    // K5: S1@W1b -> h (fp16, bias gated by deg, relu)
    gemm_h<3><<<dim3(MT, HID / GBN), 256, 0, stream>>>(
        S1, N, HID, T1b, b1b, cnt_p, CPAD, 1, nullptr, h_h, nullptr, HID, 0);

    // K6: layer-2 merged projection (Nc=256: [P2t fp16+b2a | P2b fp16])
    gemm_h<1><<<dim3(MT, (2 * OUTD) / GBN), 256, 0, stream>>>(
        h_h, N, HID, T2a, b2a, nullptr, 0, 0, nullptr, P2t, P2b, 2 * OUTD, OUTD);

    // K7: agg layer 2
    agg_f<OUTD><<<AG, 256, 0, stream>>>(P2t, P2b, cnt_p, csr, S2, N);

    // K8: final GEMM -> f32 out (+b2b gated by deg)
    gemm_h<0><<<dim3(MT, OUTD / GBN), 256, 0, stream>>>(
        S2, N, OUTD, T2b, b2b, cnt_p, CPAD, 0, (float*)d_out, nullptr, nullptr, OUTD, 0);
}

// Round 22
// 173.011 us; speedup vs baseline: 1.0848x; 1.0130x over previous
//
#include <hip/hip_runtime.h>

// GraphEncoder: 2-layer GNN, edge-MLP + scatter-mean.
//   cat(x_dst,x_src)@Wa = (x@Wa_top)[dst] + (x@Wa_bot)[src]
//   mean_agg(relu(pre)@Wb + bb) = mean_agg(relu(pre))@Wb + (cnt>0)*bb
// R22: R21 champion + agg inner loop processes TWO 8-edge groups per iteration
//      (16 row-gathers in flight per wave, was 8) — R20/R21 counters showed agg
//      at 3.2TB/s, VALUBusy 20%: not enough memory-level parallelism per wave.

#define NODE_DIM 128
#define HID 256
#define OUTD 128
#define CPAD 16    // ints per counter (64B line)
#define SLOTS 128  // csr slots per node (max deg ~60 for Poisson(32); guarded)

typedef __attribute__((ext_vector_type(8))) _Float16 f16x8;
typedef __attribute__((ext_vector_type(4))) float f32x4;
typedef __attribute__((ext_vector_type(2))) _Float16 h2;

__device__ __forceinline__ h2 bc2(unsigned u) {
    return __builtin_bit_cast(h2, u);
}
__device__ __forceinline__ ushort f2h(float x) {
    _Float16 h = (_Float16)x;
    return __builtin_bit_cast(ushort, h);
}

// ---------------- prep ----------------
// Fused: x -> fp16, weight transposes -> fp16, padded counter zero.
__global__ void prep_all(const float* __restrict__ x, int nx4,
                         ushort* __restrict__ x_h,
                         const float* __restrict__ W1a, const float* __restrict__ W1b,
                         const float* __restrict__ W2a, const float* __restrict__ W2b,
                         ushort* __restrict__ T1a, ushort* __restrict__ T1b,
                         ushort* __restrict__ T2a, ushort* __restrict__ T2b,
                         int* __restrict__ cnt_p, int N) {
    int i = blockIdx.x * blockDim.x + threadIdx.x;
    if (i < nx4) {
        float4 v = ((const float4*)x)[i];
        ushort4 h;
        h.x = f2h(v.x);
        h.y = f2h(v.y);
        h.z = f2h(v.z);
        h.w = f2h(v.w);
        ((ushort4*)x_h)[i] = h;
        return;
    }
    int j = i - nx4;
    if (j < 65536) {  // T1a [n<512][k<128]; src W1a [256][256]
        int n = j >> 7, k = j & 127;
        float v = (n < 256) ? W1a[k * 256 + n] : W1a[(128 + k) * 256 + (n - 256)];
        T1a[j] = f2h(v);
        return;
    }
    if (j < 131072) {  // T1b [n<256][k<256]; src W1b [256][256]
        int t = j - 65536;
        int n = t >> 8, k = t & 255;
        T1b[t] = f2h(W1b[k * 256 + n]);
        return;
    }
    if (j < 196608) {  // T2a [n<256][k<256]; src W2a [512][128]
        int t = j - 131072;
        int n = t >> 8, k = t & 255;
        float v = (n < 128) ? W2a[k * 128 + n] : W2a[(256 + k) * 128 + (n - 128)];
        T2a[t] = f2h(v);
        return;
    }
    if (j < 212992) {  // T2b [n<128][k<128]; src W2b [128][128]
        int t = j - 196608;
        int n = t >> 7, k = t & 127;
        T2b[t] = f2h(W2b[k * 128 + n]);
        return;
    }
    int k = j - 212992;
    if (k < N * CPAD) cnt_p[k] = 0;
}

// ---------------- one-pass fixed-stride CSR build ----------------
// csr[dst*SLOTS + p] = src, p = atomicAdd(padded cursor). No hist, no scan.
__global__ void scatter_hist(const int* __restrict__ src, const int* __restrict__ dst,
                             int* __restrict__ cnt_p, int* __restrict__ csr, int E) {
    int e = blockIdx.x * blockDim.x + threadIdx.x;
    if (e < E) {
        const int d = dst[e];
        int p = atomicAdd(&cnt_p[(size_t)d * CPAD], 1);
        if (p < SLOTS) csr[(size_t)d * SLOTS + p] = src[e];
    }
}

// ---------------- fp16 1-pass MFMA GEMM ----------------
// A[M][K] fp16; B transposed [Nc][K] fp16. Tile BM=128, BN=128, BK=32; 4 waves
// (2m x 2n), wave tile 64x64. MODE 0: f32 out (+bias*gate). MODE 1: dual fp16 —
// col<nsplit -> Ch (fp16, +bias); col>=nsplit -> Ch2 (fp16). MODE 3: fp16 out
// (+bias*gate, relu). gate is a strided int array (gate[row*gstride] > 0).

#define GBM 128
#define GBN 128
#define GBK 32
#define LDSW 40

template <int MODE>
__global__ __launch_bounds__(256) void gemm_h(
    const ushort* __restrict__ A, int M, int K,
    const ushort* __restrict__ BT,
    const float* __restrict__ bias, const int* __restrict__ gate, int gstride,
    int relu, float* __restrict__ Cf, ushort* __restrict__ Ch,
    ushort* __restrict__ Ch2, int Nc, int nsplit) {
    __shared__ ushort sA[GBM * LDSW];
    __shared__ ushort sB[GBN * LDSW];

    const int tid = threadIdx.x;
    const int lane = tid & 63;
    const int w = tid >> 6;
    const int wm = w >> 1, wn = w & 1;
    const int r16 = lane & 15, kg = lane >> 4;
    const int m0 = blockIdx.x * GBM;
    const int n0 = blockIdx.y * GBN;

    const int arow = tid >> 1, ahalf = tid & 1;  // 2 thr/row, 16 ushorts (2x int4)

    f32x4 acc[4][4];
#pragma unroll
    for (int i = 0; i < 4; i++)
#pragma unroll
        for (int j = 0; j < 4; j++) acc[i][j] = (f32x4)0.f;

    for (int kt = 0; kt < K; kt += GBK) {
        {
            const int gr = m0 + arow;
            const size_t go = (size_t)gr * K + kt + ahalf * 16;
            int4 a0 = make_int4(0, 0, 0, 0), a1 = a0;
            if (gr < M) {
                a0 = *(const int4*)(A + go);
                a1 = *(const int4*)(A + go + 8);
            }
            ushort* d = sA + arow * LDSW + ahalf * 16;
            *(int4*)(d) = a0;
            *(int4*)(d + 8) = a1;
        }
        {
            const size_t go = (size_t)(n0 + arow) * K + kt + ahalf * 16;
            int4 b0 = *(const int4*)(BT + go);
            int4 b1 = *(const int4*)(BT + go + 8);
            ushort* d = sB + arow * LDSW + ahalf * 16;
            *(int4*)(d) = b0;
            *(int4*)(d + 8) = b1;
        }
        __syncthreads();

        f16x8 av[4], bv[4];
#pragma unroll
        for (int mi = 0; mi < 4; mi++)
            av[mi] = *(const f16x8*)(sA + (wm * 64 + mi * 16 + r16) * LDSW + kg * 8);
#pragma unroll
        for (int ni = 0; ni < 4; ni++)
            bv[ni] = *(const f16x8*)(sB + (wn * 64 + ni * 16 + r16) * LDSW + kg * 8);
#pragma unroll
        for (int mi = 0; mi < 4; mi++)
#pragma unroll
            for (int ni = 0; ni < 4; ni++)
                acc[mi][ni] = __builtin_amdgcn_mfma_f32_16x16x32_f16(av[mi], bv[ni], acc[mi][ni], 0, 0, 0);
        __syncthreads();
    }

    // epilogue: C/D mapping col=lane&15, row=(lane>>4)*4+reg  [m89-verified]
#pragma unroll
    for (int ni = 0; ni < 4; ni++) {
        const int col = n0 + wn * 64 + ni * 16 + r16;
        float bv = 0.f;
        if constexpr (MODE == 1) {
            bv = (col < nsplit && bias) ? bias[col] : 0.f;
        } else {
            bv = bias ? bias[col] : 0.f;
        }
#pragma unroll
        for (int mi = 0; mi < 4; mi++) {
#pragma unroll
            for (int r = 0; r < 4; r++) {
                const int row = m0 + wm * 64 + mi * 16 + kg * 4 + r;
                if (row >= M) continue;
                if constexpr (MODE == 1) {
                    const float v = acc[mi][ni][r];
                    if (col < nsplit) {
                        Ch[(size_t)row * nsplit + col] = f2h(v + bv);
                    } else {
                        Ch2[(size_t)row * (Nc - nsplit) + (col - nsplit)] = f2h(v);
                    }
                } else {
                    float g = 1.f;
                    if (gate) g = (gate[(size_t)row * gstride] > 0) ? 1.f : 0.f;
                    float v = acc[mi][ni][r] + bv * g;
                    if (relu) v = fmaxf(v, 0.f);
                    const size_t o = (size_t)row * Nc + col;
                    if constexpr (MODE == 0) {
                        Cf[o] = v;
                    } else {
                        Ch[o] = f2h(v);
                    }
                }
            }
        }
    }
}

// ---------------- CSR mean aggregation: full-row waves, deep-batched ----------
// Wave = one node's full H-feature row (lane = feature column, VPL feats/lane).
// 2 waves per node split the edge list by 8-edge groups; each iteration now
// processes TWO groups (16 wave-uniform edge indices, 16 coalesced row-gathers
// in flight). Packed fp16 math, f32 flush per group. Fixed-stride CSR.

template <int H>
__global__ __launch_bounds__(256) void agg_f(const ushort* __restrict__ Ptop,
                                             const ushort* __restrict__ Pbot,
                                             const int* __restrict__ cnt_p,
                                             const int* __restrict__ csr,
                                             ushort* __restrict__ S, int N) {
    constexpr int VPL = H / 64;  // feats per lane: 4 (H=256) or 2 (H=128)
    __shared__ float red[2][64 * VPL];

    const int tid = threadIdx.x;
    const int lane = tid & 63;
    const int wv = __builtin_amdgcn_readfirstlane(tid >> 6);
    const int nb = wv >> 1;   // node within block (0,1)
    const int sub = wv & 1;   // edge-split half
    int n = blockIdx.x * 2 + nb;
    if (n >= N) n = N - 1;  // benign duplicate on tail

    int deg = cnt_p[(size_t)n * CPAD];
    if (deg > SLOTS) deg = SLOTS;  // impossible for this input; guards OOB
    const int begin = n * SLOTS;

    h2 t01, t23;
    if constexpr (VPL == 4) {
        uint2 tu = *(const uint2*)(Ptop + (size_t)n * H + lane * 4);
        t01 = bc2(tu.x);
        t23 = bc2(tu.y);
    } else {
        unsigned tu = *(const unsigned*)(Ptop + (size_t)n * H + lane * 2);
        t01 = bc2(tu);
        t23 = t01;
    }
    const h2 z2 = (h2)(_Float16)0.f;

    float a0 = 0.f, a1 = 0.f, a2 = 0.f, a3 = 0.f;
    const ushort* pb = Pbot + lane * VPL;

    const int Gf = deg >> 3;  // full 8-edge groups
    const int r = deg & 7;

    int g = sub;
    // two groups per iteration: 16 gathers in flight
    for (; g + 2 < Gf; g += 4) {
        const int e0 = begin + g * 8;
        const int e1 = begin + (g + 2) * 8;
        int idx[16];
#pragma unroll
        for (int j = 0; j < 8; j++) idx[j] = csr[e0 + j];
#pragma unroll
        for (int j = 0; j < 8; j++) idx[8 + j] = csr[e1 + j];
        if constexpr (VPL == 4) {
            uint2 v[16];
#pragma unroll
            for (int j = 0; j < 16; j++)
                v[j] = *(const uint2*)(pb + (size_t)idx[j] * H);
            h2 p01a = z2, p23a = z2, p01b = z2, p23b = z2;
#pragma unroll
            for (int j = 0; j < 8; j++) {
                p01a += __builtin_elementwise_max(t01 + bc2(v[j].x), z2);
                p23a += __builtin_elementwise_max(t23 + bc2(v[j].y), z2);
                p01b += __builtin_elementwise_max(t01 + bc2(v[8 + j].x), z2);
                p23b += __builtin_elementwise_max(t23 + bc2(v[8 + j].y), z2);
            }
            a0 += (float)p01a.x + (float)p01b.x;
            a1 += (float)p01a.y + (float)p01b.y;
            a2 += (float)p23a.x + (float)p23b.x;
            a3 += (float)p23a.y + (float)p23b.y;
        } else {
            unsigned v[16];
#pragma unroll
            for (int j = 0; j < 16; j++)
                v[j] = *(const unsigned*)(pb + (size_t)idx[j] * H);
            h2 p01a = z2, p01b = z2;
#pragma unroll
            for (int j = 0; j < 8; j++) {
                p01a += __builtin_elementwise_max(t01 + bc2(v[j]), z2);
                p01b += __builtin_elementwise_max(t01 + bc2(v[8 + j]), z2);
            }
            a0 += (float)p01a.x + (float)p01b.x;
            a1 += (float)p01a.y + (float)p01b.y;
        }
    }
    // remaining single full group (if any)
    for (; g < Gf; g += 2) {
        const int e = begin + g * 8;
        h2 p01 = z2, p23 = z2;
#pragma unroll
        for (int j = 0; j < 8; j++) {
            const int idx = csr[e + j];
            if constexpr (VPL == 4) {
                uint2 u = *(const uint2*)(pb + (size_t)idx * H);
                p01 += __builtin_elementwise_max(t01 + bc2(u.x), z2);
                p23 += __builtin_elementwise_max(t23 + bc2(u.y), z2);
            } else {
                unsigned u = *(const unsigned*)(pb + (size_t)idx * H);
                p01 += __builtin_elementwise_max(t01 + bc2(u), z2);
            }
        }
        a0 += (float)p01.x;
        a1 += (float)p01.y;
        if constexpr (VPL == 4) {
            a2 += (float)p23.x;
            a3 += (float)p23.y;
        }
    }
    if (r && sub == (Gf & 1)) {  // tail (<8 edges) to the wave with fewer groups
        const int e = begin + Gf * 8;
        h2 p01 = z2, p23 = z2;
        for (int j = 0; j < r; j++) {
            const int idx = csr[e + j];
            if constexpr (VPL == 4) {
                uint2 u = *(const uint2*)(pb + (size_t)idx * H);
                p01 += __builtin_elementwise_max(t01 + bc2(u.x), z2);
                p23 += __builtin_elementwise_max(t23 + bc2(u.y), z2);
            } else {
                unsigned u = *(const unsigned*)(pb + (size_t)idx * H);
                p01 += __builtin_elementwise_max(t01 + bc2(u), z2);
            }
        }
        a0 += (float)p01.x;
        a1 += (float)p01.y;
        if constexpr (VPL == 4) {
            a2 += (float)p23.x;
            a3 += (float)p23.y;
        }
    }

    // combine the two edge-split waves via LDS
    if (sub == 1) {
        red[nb][lane * VPL + 0] = a0;
        red[nb][lane * VPL + 1] = a1;
        if constexpr (VPL == 4) {
            red[nb][lane * VPL + 2] = a2;
            red[nb][lane * VPL + 3] = a3;
        }
    }
    __syncthreads();
    if (sub == 0) {
        a0 += red[nb][lane * VPL + 0];
        a1 += red[nb][lane * VPL + 1];
        if constexpr (VPL == 4) {
            a2 += red[nb][lane * VPL + 2];
            a3 += red[nb][lane * VPL + 3];
        }
        const float inv = (deg > 0) ? 1.f / (float)deg : 0.f;
        if constexpr (VPL == 4) {
            ushort4 h;
            h.x = f2h(a0 * inv);
            h.y = f2h(a1 * inv);
            h.z = f2h(a2 * inv);
            h.w = f2h(a3 * inv);
            *(ushort4*)(S + (size_t)n * H + lane * 4) = h;
        } else {
            ushort2 h;
            h.x = f2h(a0 * inv);
            h.y = f2h(a1 * inv);
            *(ushort2*)(S + (size_t)n * H + lane * 2) = h;
        }
    }
}

// ---------------- launch ----------------

extern "C" void kernel_launch(void* const* d_in, const int* in_sizes, int n_in,
                              void* d_out, int out_size, void* d_ws, size_t ws_size,
                              hipStream_t stream) {
    const int N = in_sizes[0] / NODE_DIM;  // 20000
    const int E = in_sizes[1] / 2;         // 640000

    const float* x = (const float*)d_in[0];
    const int* ei = (const int*)d_in[1];
    const int* e_src = ei;
    const int* e_dst = ei + E;
    const float* W1a = (const float*)d_in[2];
    const float* b1a = (const float*)d_in[3];
    const float* W1b = (const float*)d_in[4];
    const float* b1b = (const float*)d_in[5];
    const float* W2a = (const float*)d_in[6];
    const float* b2a = (const float*)d_in[7];
    const float* W2b = (const float*)d_in[8];
    const float* b2b = (const float*)d_in[9];

    char* ws = (char*)d_ws;
    size_t off = 0;
    auto alloc = [&](size_t bytes) {
        size_t o = off;
        off += (bytes + 255) & ~(size_t)255;
        return o;
    };
    int* cnt_p = (int*)(ws + alloc((size_t)N * CPAD * 4));  // padded cursors/counts
    int* csr = (int*)(ws + alloc((size_t)N * SLOTS * 4));   // fixed-stride CSR
    ushort* x_h = (ushort*)(ws + alloc((size_t)N * NODE_DIM * 2));
    ushort* T1a = (ushort*)(ws + alloc((size_t)(2 * HID) * NODE_DIM * 2));  // [512][128]
    ushort* T1b = (ushort*)(ws + alloc((size_t)HID * HID * 2));
    ushort* T2a = (ushort*)(ws + alloc((size_t)(2 * OUTD) * HID * 2));  // [256][256]
    ushort* T2b = (ushort*)(ws + alloc((size_t)OUTD * OUTD * 2));
    ushort* P1t = (ushort*)(ws + alloc((size_t)N * HID * 2));   // fp16
    ushort* P1b = (ushort*)(ws + alloc((size_t)N * HID * 2));   // fp16
    ushort* P2b = (ushort*)(ws + alloc((size_t)N * OUTD * 2));  // fp16
    ushort* S1 = (ushort*)(ws + alloc((size_t)N * HID * 2));    // fp16
    ushort* S2 = (ushort*)(ws + alloc((size_t)N * OUTD * 2));   // fp16
    ushort* h_h = (ushort*)(ws + alloc((size_t)N * HID * 2));   // fp16
    ushort* P2t = P1t;

    const int MT = (N + GBM - 1) / GBM;  // 157
    const int AG = (N + 1) / 2;          // agg blocks: 2 nodes x 2 edge-split waves

    // K1: prep (padded counter zero inside)
    const int nx4 = N * NODE_DIM / 4;
    const int prep_n = nx4 + 212992 + N * CPAD;
    prep_all<<<(prep_n + 255) / 256, 256, 0, stream>>>(
        x, nx4, x_h, W1a, W1b, W2a, W2b, T1a, T1b, T2a, T2b, cnt_p, N);

    // K2: one-pass CSR build (hist+scan+scatter collapsed)
    scatter_hist<<<(E + 255) / 256, 256, 0, stream>>>(e_src, e_dst, cnt_p, csr, E);

    // K3: layer-1 merged projection (Nc=512: [P1t fp16+b1a | P1b fp16])
    gemm_h<1><<<dim3(MT, (2 * HID) / GBN), 256, 0, stream>>>(
        x_h, N, NODE_DIM, T1a, b1a, nullptr, 0, 0, nullptr, P1t, P1b, 2 * HID, HID);

    // K4: agg layer 1
    agg_f<HID><<<AG, 256, 0, stream>>>(P1t, P1b, cnt_p, csr, S1, N);

    // K5: S1@W1b -> h (fp16, bias gated by deg, relu)
    gemm_h<3><<<dim3(MT, HID / GBN), 256, 0, stream>>>(
        S1, N, HID, T1b, b1b, cnt_p, CPAD, 1, nullptr, h_h, nullptr, HID, 0);

    // K6: layer-2 merged projection (Nc=256: [P2t fp16+b2a | P2b fp16])
    gemm_h<1><<<dim3(MT, (2 * OUTD) / GBN), 256, 0, stream>>>(
        h_h, N, HID, T2a, b2a, nullptr, 0, 0, nullptr, P2t, P2b, 2 * OUTD, OUTD);

    // K7: agg layer 2
    agg_f<OUTD><<<AG, 256, 0, stream>>>(P2t, P2b, cnt_p, csr, S2, N);

    // K8: final GEMM -> f32 out (+b2b gated by deg)
    gemm_h<0><<<dim3(MT, OUTD / GBN), 256, 0, stream>>>(
        S2, N, OUTD, T2b, b2b, cnt_p, CPAD, 0, (float*)d_out, nullptr, nullptr, OUTD, 0);
}